// Round 6
// baseline (3263.273 us; speedup 1.0000x reference)
//
#include <hip/hip_runtime.h>
#include <stdint.h>

#define NPER  25000
#define NNODE 50000
#define NEDGE 600000
#define NREL  8
#define NBASE 4
#define INDIM 256
#define HIDD  128
#define OUTD  64
#define NSEG  (NNODE * NREL)
#define NTILE (NNODE / 16)                  // 3125 conv tiles
#define NCHUNK ((NSEG + 1 + 1023) / 1024)   // 391 scan chunks
#define NBLK  2048                          // 256 CU x 8 blocks/CU: all co-resident by construction

typedef unsigned short u16;
typedef unsigned int   u32;
typedef __attribute__((ext_vector_type(8))) __bf16          bf16x8;
typedef __attribute__((ext_vector_type(8))) unsigned short  ushort8;
typedef __attribute__((ext_vector_type(4))) float           f32x4;
typedef __attribute__((ext_vector_type(2))) float           f32x2;

__device__ __forceinline__ u16 f2b(float f) {
    union { __bf16 h; u16 u; } v; v.h = (__bf16)f; return v.u;   // HW RNE cvt
}
__device__ __forceinline__ bf16x8 as_bf(ushort8 u) {
    union { ushort8 a; bf16x8 b; } v; v.a = u; return v.b;
}
__device__ __forceinline__ bf16x8 cvt8(const float* p) {
    f32x4 f0 = *(const f32x4*)p;
    f32x4 f1 = *(const f32x4*)(p + 4);
    ushort8 u;
#pragma unroll
    for (int i = 0; i < 4; i++) { u[i] = f2b(f0[i]); u[i + 4] = f2b(f1[i]); }
    return as_bf(u);
}
__device__ __forceinline__ float blo(u32 v) {
    union { u32 i; float f; } u; u.i = v << 16; return u.f;
}
__device__ __forceinline__ float bhi(u32 v) {
    union { u32 i; float f; } u; u.i = v & 0xffff0000u; return u.f;
}

// ---------------- manual grid barrier (all NBLK blocks co-resident by construction) ----------------
// release fence -> arrive (device-scope atomic) -> bounded spin -> acquire fence.
// Bounded spin (~28 ms) turns a broken-assumption deadlock into a wrong-answer,
// not a container hang.
__device__ __forceinline__ void gsync(int* bar, int target) {
    __syncthreads();
    __threadfence();                       // release: every wave's stores device-visible
    __syncthreads();                       // all waves' fences retired before signal
    if (threadIdx.x == 0) {
        atomicAdd(bar, 1);                 // device-scope by default on global mem
        int spins = 0;
        while (__hip_atomic_load(bar, __ATOMIC_RELAXED, __HIP_MEMORY_SCOPE_AGENT) < target) {
            __builtin_amdgcn_s_sleep(32);
            if (++spins > (1 << 15)) break;    // safety escape
        }
    }
    __syncthreads();
    __threadfence();                       // acquire: invalidate L1 so remote stores visible
}

// ---------------- Bsw repack element mappers (unchanged math) ----------------
__device__ __forceinline__ void bsw_proj_elem(const float* __restrict__ W, u16* __restrict__ out, int idx) {
    int j    = idx & 7;
    int lane = (idx >> 3) & 63;
    int rest = idx >> 9;
    int nt   = rest & 7;
    int ks   = rest >> 3;
    int col  = nt * 16 + (lane & 15);
    int k    = ks * 32 + ((lane >> 4) << 3) + j;
    out[idx] = f2b(W[(size_t)k * 128 + col]);
}
__device__ __forceinline__ void bsw_conv_elem(const float* __restrict__ bases, const float* __restrict__ root,
                                              int ncol, u16* __restrict__ out, int idx) {
    int nt_cnt = ncol >> 4;
    int j    = idx & 7;
    int lane = (idx >> 3) & 63;
    int rest = idx >> 9;
    int nt   = rest % nt_cnt;
    int ks   = rest / nt_cnt;
    int col  = nt * 16 + (lane & 15);
    int k    = ks * 32 + ((lane >> 4) << 3) + j;
    float v = (k < 512) ? bases[(size_t)k * ncol + col] : root[(size_t)(k - 512) * ncol + col];
    out[idx] = f2b(v);
}

// ---------------- fused kernel 1: Bsw repack + CSR build (replaces 7 dispatches) ----------------
__global__ __launch_bounds__(256, 8) void csr_fused(
    const float* __restrict__ Wp, const float* __restrict__ Wa,
    const float* __restrict__ bases0, const float* __restrict__ root0,
    const float* __restrict__ bases1, const float* __restrict__ root1,
    const float* __restrict__ bases2, const float* __restrict__ root2,
    u16* __restrict__ Bswp, u16* __restrict__ Bswa,
    u16* __restrict__ Bswc0, u16* __restrict__ Bswc1, u16* __restrict__ Bswc2,
    const int* __restrict__ ei, const int* __restrict__ et,
    int* __restrict__ rowptr, int* __restrict__ fill,
    int* __restrict__ epk, int* __restrict__ bsum, int* __restrict__ bar) {
    __shared__ int sh[256];
    int t = threadIdx.x;
    int gtid  = blockIdx.x * 256 + t;
    int gsize = gridDim.x * 256;
    int nb    = gridDim.x;

    // ---- P0: Bsw repack (1056 block-units) + zero rowptr ----
    for (int b = blockIdx.x; b < 1056; b += gridDim.x) {
        if (b < 128)       bsw_proj_elem(Wp, Bswp, b * 256 + t);
        else if (b < 256)  bsw_proj_elem(Wa, Bswa, (b - 128) * 256 + t);
        else if (b < 576)  bsw_conv_elem(bases0, root0, HIDD, Bswc0, (b - 256) * 256 + t);
        else if (b < 896)  bsw_conv_elem(bases1, root1, HIDD, Bswc1, (b - 576) * 256 + t);
        else               bsw_conv_elem(bases2, root2, OUTD, Bswc2, (b - 896) * 256 + t);
    }
    for (int i = gtid; i <= NSEG; i += gsize) rowptr[i] = 0;
    gsync(bar, 1 * nb);

    // ---- P1: histogram over (dst, rel) ----
    for (int e = gtid; e < NEDGE; e += gsize) {
        int dst = ei[NEDGE + e];
        int r   = et[e];
        atomicAdd(&rowptr[dst * NREL + r], 1);
    }
    gsync(bar, 2 * nb);

    // ---- P2: scan1 (per-chunk exclusive scan, chunk sums -> bsum) ----
    for (int c = blockIdx.x; c < NCHUNK; c += gridDim.x) {
        int base = c * 1024 + t * 4;
        int v[4];
#pragma unroll
        for (int i = 0; i < 4; i++) v[i] = (base + i <= NSEG) ? rowptr[base + i] : 0;
        int tot = v[0] + v[1] + v[2] + v[3];
        sh[t] = tot; __syncthreads();
        for (int off = 1; off < 256; off <<= 1) {
            int x = (t >= off) ? sh[t - off] : 0;
            __syncthreads();
            sh[t] += x;
            __syncthreads();
        }
        int excl = sh[t] - tot;
        if (t == 255) bsum[c] = sh[255];
        int run = excl;
#pragma unroll
        for (int i = 0; i < 4; i++) {
            if (base + i <= NSEG) rowptr[base + i] = run;
            run += v[i];
        }
        __syncthreads();
    }
    gsync(bar, 3 * nb);

    // ---- P3: scan2 over NCHUNK partials (block 0, 2 elems/thread) ----
    if (blockIdx.x == 0) {
        int a0 = (2 * t     < NCHUNK) ? bsum[2 * t]     : 0;
        int a1 = (2 * t + 1 < NCHUNK) ? bsum[2 * t + 1] : 0;
        int s = a0 + a1;
        sh[t] = s; __syncthreads();
        for (int off = 1; off < 256; off <<= 1) {
            int x = (t >= off) ? sh[t - off] : 0;
            __syncthreads();
            sh[t] += x;
            __syncthreads();
        }
        int excl = sh[t] - s;
        if (2 * t     < NCHUNK) bsum[2 * t]     = excl;
        if (2 * t + 1 < NCHUNK) bsum[2 * t + 1] = excl + a0;
    }
    gsync(bar, 4 * nb);

    // ---- P4: scan3 (add block offsets, materialize fill) ----
    for (int c = blockIdx.x; c < NCHUNK; c += gridDim.x) {
        int add = bsum[c];
        int base = c * 1024 + t * 4;
#pragma unroll
        for (int i = 0; i < 4; i++) {
            int idx = base + i;
            if (idx <= NSEG) {
                int v = rowptr[idx] + add;
                rowptr[idx] = v;
                if (idx < NSEG) fill[idx] = v;
            }
        }
    }
    gsync(bar, 5 * nb);

    // ---- P5: scatter edges into (dst, rel)-grouped runs ----
    for (int e = gtid; e < NEDGE; e += gsize) {
        int src = ei[e];
        int dst = ei[NEDGE + e];
        int r   = et[e];
        int pos = atomicAdd(&fill[dst * NREL + r], 1);
        epk[pos] = src | (r << 16);
    }
}

// ---------------- fused conv tile body (identical math to R4 fused_conv16) ----------------
template<int NT, bool RELU, bool RES>
__device__ __forceinline__ void conv_tile(
    int blk, char* AsB, float (*wtab)[4][40],
    const u16* __restrict__ xbf, const float* __restrict__ comp,
    const int* __restrict__ rowptr, const int* __restrict__ epk,
    const u16* __restrict__ Bsw, const float* __restrict__ bias,
    float* __restrict__ out1, u16* __restrict__ outb,
    const float* __restrict__ resid, int ldo) {
    int tid  = threadIdx.x;
    int wv   = __builtin_amdgcn_readfirstlane(tid >> 6);
    int lane = tid & 63;
    int co   = lane * 2;
    float compv = (lane < 32) ? comp[lane] : 0.f;
    const int INV = 8 << 16;               // sentinel: src=0, rel=8 (zero weight)
    const u16* xco = xbf + co;

    int nbase = blk * 16 + wv * 4;

    // hoisted per-node state
    int p[4], e[4];
#pragma unroll
    for (int i = 0; i < 4; i++) {
        int rbase = (nbase + i) * NREL;
        if (lane < 36) {
            float w = 0.f;
            if (lane < 32) {
                int r   = lane >> 2;
                int c0  = rowptr[rbase + r], c1 = rowptr[rbase + r + 1];
                int cnt = c1 - c0;
                w = compv * ((cnt > 0) ? 1.f / (float)cnt : 0.f);
            }
            wtab[wv][i][lane] = w;
        }
        p[i] = __builtin_amdgcn_readfirstlane(rowptr[rbase]);
        e[i] = __builtin_amdgcn_readfirstlane(rowptr[rbase + 8]);
    }

    // phase 1: aggregate 4 nodes per wave into LDS (8-deep pipelined walk)
#pragma unroll
    for (int i = 0; i < 4; i++) {
        int lr = wv * 4 + i;
        const char* wt = (const char*)&wtab[wv][i][0];
        f32x2 av[4];
#pragma unroll
        for (int b = 0; b < 4; b++) av[b] = (f32x2){0.f, 0.f};
        int k0[8]; u32 v0[8];
#pragma unroll
        for (int j = 0; j < 8; j++) k0[j] = (p[i] + j < e[i]) ? epk[p[i] + j] : INV;
#pragma unroll
        for (int j = 0; j < 8; j++) v0[j] = *(const u32*)(xco + ((size_t)(k0[j] & 0xffff) << 7));
        for (int pc = p[i]; pc < e[i]; pc += 8) {
            int pn = pc + 8;
            int k1[8]; u32 v1[8];
#pragma unroll
            for (int j = 0; j < 8; j++) k1[j] = (pn + j < e[i]) ? epk[pn + j] : INV;
#pragma unroll
            for (int j = 0; j < 8; j++) v1[j] = *(const u32*)(xco + ((size_t)(k1[j] & 0xffff) << 7));
#pragma unroll
            for (int j = 0; j < 8; j++) {
                f32x4 w = *(const f32x4*)(wt + (((u32)k0[j] >> 16) << 4));
                f32x2 x2; x2.x = blo(v0[j]); x2.y = bhi(v0[j]);
                av[0] += w[0] * x2;
                av[1] += w[1] * x2;
                av[2] += w[2] * x2;
                av[3] += w[3] * x2;
            }
#pragma unroll
            for (int j = 0; j < 8; j++) { k0[j] = k1[j]; v0[j] = v1[j]; }
        }
        u32 swz = (u32)(lr & 7) << 4;
        char* rowp = AsB + lr * 1024;
#pragma unroll
        for (int b = 0; b < 4; b++) {
            u32 pk = (u32)f2b(av[b].x) | ((u32)f2b(av[b].y) << 16);
            *(u32*)(rowp + (((u32)(b * 256 + lane * 4)) ^ swz)) = pk;
        }
    }
    __syncthreads();

    // phase 2: [16 x 640] @ [640 x NT*16] MFMA; wave handles NT/4 col tiles
    constexpr int NTW = NT / 4;
    int l15 = lane & 15, quad = lane >> 4;
    int rowbase = blk * 16;
    int xrow = rowbase + l15;
    const u16*  bp   = Bsw + lane * 8;
    const char* arow = AsB + l15 * 1024;
    u32 swz2 = (u32)(l15 & 7) << 4;
    f32x4 acc[NTW];
#pragma unroll
    for (int n = 0; n < NTW; n++) acc[n] = (f32x4){0.f, 0.f, 0.f, 0.f};
#pragma unroll
    for (int ks = 0; ks < 20; ks++) {
        bf16x8 a;
        if (ks < 16) a = *(const bf16x8*)(arow + (((u32)(ks * 64 + quad * 16)) ^ swz2));
        else         a = as_bf(*(const ushort8*)(xbf + (size_t)xrow * 128 + (ks - 16) * 32 + quad * 8));
#pragma unroll
        for (int n = 0; n < NTW; n++) {
            int nt = wv * NTW + n;
            bf16x8 b = as_bf(*(const ushort8*)(bp + ((size_t)(ks * NT + nt) << 9)));
            acc[n] = __builtin_amdgcn_mfma_f32_16x16x32_bf16(a, b, acc[n], 0, 0, 0);
        }
    }
    int orow0 = rowbase + quad * 4;
#pragma unroll
    for (int r = 0; r < 4; r++) {
        int orow = orow0 + r;
#pragma unroll
        for (int n = 0; n < NTW; n++) {
            int col = (wv * NTW + n) * 16 + l15;
            float v = acc[n][r] + bias[col];
            if (RELU) v = v > 0.f ? v : 0.f;
            if (RES)  v += resid[(size_t)orow * ldo + col];
            size_t oi = (size_t)orow * ldo + col;
            if (out1) out1[oi] = v;
            if (outb) outb[oi] = f2b(v);
        }
    }
    __syncthreads();   // protect LDS tile across grid-stride iterations
}

// ---------------- fused kernel 2: all 3 convs with manual grid barriers ----------------
__global__ __launch_bounds__(256, 8) void conv3_fused(
    u16* __restrict__ xbf0, u16* __restrict__ xbf1,
    const float* __restrict__ comp0, const float* __restrict__ comp1, const float* __restrict__ comp2,
    const int* __restrict__ rowptr, const int* __restrict__ epk,
    const u16* __restrict__ Bswc0, const u16* __restrict__ Bswc1, const u16* __restrict__ Bswc2,
    const float* __restrict__ bias0, const float* __restrict__ bias1, const float* __restrict__ bias2,
    float* __restrict__ lat2, float* __restrict__ outF, int* __restrict__ bar) {
    __shared__ char AsB[16 * 1024];        // 16 KB bf16 A tile
    __shared__ float wtab[4][4][40];
    int nb = gridDim.x;

    // conv0: x1 = relu(rgcn(x0)) -> lat2 (fp32) + xbf1 (bf16)
    for (int tl = blockIdx.x; tl < NTILE; tl += gridDim.x)
        conv_tile<8, true, false>(tl, AsB, wtab, xbf0, comp0, rowptr, epk,
                                  Bswc0, bias0, lat2, xbf1, nullptr, HIDD);
    gsync(bar, 1 * nb);
    // conv1: x2 = x1 + relu(rgcn(x1)) -> xbf0 (bf16)
    for (int tl = blockIdx.x; tl < NTILE; tl += gridDim.x)
        conv_tile<8, true, true>(tl, AsB, wtab, xbf1, comp1, rowptr, epk,
                                 Bswc1, bias1, nullptr, xbf0, lat2, HIDD);
    gsync(bar, 2 * nb);
    // conv2: out = rgcn(x2) -> outF fp32
    for (int tl = blockIdx.x; tl < NTILE; tl += gridDim.x)
        conv_tile<4, false, false>(tl, AsB, wtab, xbf0, comp2, rowptr, epk,
                                   Bswc2, bias2, outF, nullptr, nullptr, OUTD);
}

// ---------------- MFMA bf16 GEMM core (projections, unchanged) ----------------
template<int KMAIN, bool HASX, int NW, int MW, int NT, bool RELU, bool RES, bool AF32>
__device__ __forceinline__ void gemm_core(
    int blk, const void* __restrict__ Av, const u16* __restrict__ xq,
    const u16* __restrict__ Bsw, const float* __restrict__ bias, int M,
    float* __restrict__ out1, float* __restrict__ out2, u16* __restrict__ outb,
    const float* __restrict__ resid, int ldo) {
    constexpr int KSM = KMAIN / 32;
    constexpr int KST = KSM + (HASX ? 4 : 0);
    int tid  = threadIdx.x;
    int wave = tid >> 6, lane = tid & 63;
    int l15  = lane & 15, quad = lane >> 4;
    int rowbase = blk * (NW * MW * 16) + wave * (MW * 16);
    int rA[MW];
#pragma unroll
    for (int m = 0; m < MW; m++) {
        rA[m] = rowbase + m * 16 + l15;
        if (rA[m] > M - 1) rA[m] = M - 1;
    }
    const u16* bp = Bsw + lane * 8;
    f32x4 acc[MW][NT];
#pragma unroll
    for (int m = 0; m < MW; m++)
#pragma unroll
        for (int i = 0; i < NT; i++) acc[m][i] = (f32x4){0.f, 0.f, 0.f, 0.f};
#pragma unroll
    for (int ks = 0; ks < KST; ks++) {
        bf16x8 a[MW];
#pragma unroll
        for (int m = 0; m < MW; m++) {
            if (ks < KSM) {
                if (AF32) a[m] = cvt8((const float*)Av + (size_t)rA[m] * KMAIN + ks * 32 + quad * 8);
                else      a[m] = as_bf(*(const ushort8*)((const u16*)Av + (size_t)rA[m] * KMAIN + ks * 32 + quad * 8));
            } else {
                a[m] = as_bf(*(const ushort8*)(xq + (size_t)rA[m] * 128 + (ks - KSM) * 32 + quad * 8));
            }
        }
#pragma unroll
        for (int nt = 0; nt < NT; nt++) {
            bf16x8 b = as_bf(*(const ushort8*)(bp + ((size_t)(ks * NT + nt) << 9)));
#pragma unroll
            for (int m = 0; m < MW; m++)
                acc[m][nt] = __builtin_amdgcn_mfma_f32_16x16x32_bf16(a[m], b, acc[m][nt], 0, 0, 0);
        }
    }
#pragma unroll
    for (int m = 0; m < MW; m++) {
        int orow0 = rowbase + m * 16 + quad * 4;
#pragma unroll
        for (int r = 0; r < 4; r++) {
            int orow = orow0 + r;
            if (orow < M) {
#pragma unroll
                for (int nt = 0; nt < NT; nt++) {
                    int col = nt * 16 + l15;
                    float v = acc[m][nt][r] + bias[col];
                    if (RELU) v = v > 0.f ? v : 0.f;
                    if (RES)  v += resid[(size_t)orow * ldo + col];
                    size_t oi = (size_t)orow * ldo + col;
                    if (out1) out1[oi] = v;
                    if (out2) out2[oi] = v;
                    if (outb) outb[oi] = f2b(v);
                }
            }
        }
    }
}

// both projections in one dispatch (gridDim.y = 2 selects paper/author)
__global__ __launch_bounds__(256, 2) void proj2_kernel(
    const float* __restrict__ xp, const float* __restrict__ xa,
    const u16* __restrict__ Bswp, const u16* __restrict__ Bswa,
    const float* __restrict__ bp, const float* __restrict__ ba,
    float* __restrict__ lat0, float* __restrict__ lat1, u16* __restrict__ xbf0) {
    int y = blockIdx.y;
    const float* A    = y ? xa : xp;
    const u16*   B    = y ? Bswa : Bswp;
    const float* bias = y ? ba : bp;
    size_t off = (size_t)y * NPER * HIDD;
    gemm_core<256, false, 4, 1, 8, true, false, true>(
        blockIdx.x, A, nullptr, B, bias, NPER, lat0 + off, lat1 + off, xbf0 + off, nullptr, HIDD);
}

extern "C" void kernel_launch(void* const* d_in, const int* in_sizes, int n_in,
                              void* d_out, int out_size, void* d_ws, size_t ws_size,
                              hipStream_t stream) {
    const float* x_paper  = (const float*)d_in[0];
    const float* x_author = (const float*)d_in[1];
    const float* W_paper  = (const float*)d_in[2];
    const float* b_paper  = (const float*)d_in[3];
    const float* W_author = (const float*)d_in[4];
    const float* b_author = (const float*)d_in[5];
    const float* bases0   = (const float*)d_in[6];
    const float* comp0    = (const float*)d_in[7];
    const float* root0    = (const float*)d_in[8];
    const float* bias0    = (const float*)d_in[9];
    const float* bases1   = (const float*)d_in[10];
    const float* comp1    = (const float*)d_in[11];
    const float* root1    = (const float*)d_in[12];
    const float* bias1    = (const float*)d_in[13];
    const float* bases2   = (const float*)d_in[14];
    const float* comp2    = (const float*)d_in[15];
    const float* root2    = (const float*)d_in[16];
    const float* bias2    = (const float*)d_in[17];
    const int* ei         = (const int*)d_in[18];
    const int* et         = (const int*)d_in[19];

    float* ob   = (float*)d_out;
    float* outF = ob;                         // [50000,64]
    float* lat0 = ob + 3200000;               // x0
    float* lat1 = ob + 9600000;               // x0 (copy)
    float* lat2 = ob + 16000000;              // x1

    char* w = (char*)d_ws;
    u16*   xbf0   = (u16*)(w + 51200000);     // 12,800,000
    u16*   xbf1   = (u16*)(w + 64000000);     // 12,800,000
    u16*   Bswc0  = (u16*)(w + 76800000);     // 163,840
    u16*   Bswc1  = (u16*)(w + 76963840);     // 163,840
    u16*   Bswc2  = (u16*)(w + 77127680);     // 81,920
    u16*   Bswp   = (u16*)(w + 77209600);     // 65,536
    u16*   Bswa   = (u16*)(w + 77275136);     // 65,536
    int*   rowptr = (int*)(w + 77340672);     // 400001*4 (pad to 1,600,064)
    int*   fill   = (int*)(w + 78940736);     // 1,600,000
    int*   epk    = (int*)(w + 80540736);     // 2,400,000
    int*   bsum   = (int*)(w + 82940736);     // 2,048
    int*   bar    = (int*)(w + 82942784);     // 64 B barrier counters (bar[0]=csr, bar[1]=conv)

    // ---- dispatch 0: zero barrier counters (workspace is poisoned each iteration) ----
    hipMemsetAsync(bar, 0, 64, stream);

    // ---- dispatch 1: Bsw repack + CSR build (manual grid barriers) ----
    csr_fused<<<NBLK, 256, 0, stream>>>(
        W_paper, W_author, bases0, root0, bases1, root1, bases2, root2,
        Bswp, Bswa, Bswc0, Bswc1, Bswc2, ei, et,
        rowptr, fill, epk, bsum, &bar[0]);

    // ---- dispatch 2: projections x0 = relu(x @ W + b) ----
    proj2_kernel<<<dim3((NPER + 63) / 64, 2), 256, 0, stream>>>(
        x_paper, x_author, Bswp, Bswa, b_paper, b_author, lat0, lat1, xbf0);

    // ---- dispatch 3: all 3 RGCN convs (manual grid barriers) ----
    conv3_fused<<<NBLK, 256, 0, stream>>>(
        xbf0, xbf1, comp0, comp1, comp2, rowptr, epk,
        Bswc0, Bswc1, Bswc2, bias0, bias1, bias2, lat2, outF, &bar[1]);
}

// Round 7
// 398.674 us; speedup vs baseline: 8.1853x; 8.1853x over previous
//
#include <hip/hip_runtime.h>
#include <stdint.h>

#define NPER  25000
#define NNODE 50000
#define NEDGE 600000
#define NREL  8
#define NBASE 4
#define INDIM 256
#define HIDD  128
#define OUTD  64
#define NSEG  (NNODE * NREL)
#define NCHUNK ((NSEG + 1 + 1023) / 1024)   // 391 scan chunks
#define RDY   0x80000000u

typedef unsigned short u16;
typedef unsigned int   u32;
typedef __attribute__((ext_vector_type(8))) __bf16          bf16x8;
typedef __attribute__((ext_vector_type(8))) unsigned short  ushort8;
typedef __attribute__((ext_vector_type(4))) float           f32x4;
typedef __attribute__((ext_vector_type(2))) float           f32x2;

__device__ __forceinline__ u16 f2b(float f) {
    union { __bf16 h; u16 u; } v; v.h = (__bf16)f; return v.u;   // HW RNE cvt
}
__device__ __forceinline__ bf16x8 as_bf(ushort8 u) {
    union { ushort8 a; bf16x8 b; } v; v.a = u; return v.b;
}
__device__ __forceinline__ bf16x8 cvt8(const float* p) {
    f32x4 f0 = *(const f32x4*)p;
    f32x4 f1 = *(const f32x4*)(p + 4);
    ushort8 u;
#pragma unroll
    for (int i = 0; i < 4; i++) { u[i] = f2b(f0[i]); u[i + 4] = f2b(f1[i]); }
    return as_bf(u);
}
__device__ __forceinline__ float blo(u32 v) {
    union { u32 i; float f; } u; u.i = v << 16; return u.f;
}
__device__ __forceinline__ float bhi(u32 v) {
    union { u32 i; float f; } u; u.i = v & 0xffff0000u; return u.f;
}

// ---------------- Bsw repack element mappers (unchanged math) ----------------
__device__ __forceinline__ void bsw_proj_elem(const float* __restrict__ W, u16* __restrict__ out, int idx) {
    int j    = idx & 7;
    int lane = (idx >> 3) & 63;
    int rest = idx >> 9;
    int nt   = rest & 7;
    int ks   = rest >> 3;
    int col  = nt * 16 + (lane & 15);
    int k    = ks * 32 + ((lane >> 4) << 3) + j;
    out[idx] = f2b(W[(size_t)k * 128 + col]);
}
__device__ __forceinline__ void bsw_conv_elem(const float* __restrict__ bases, const float* __restrict__ root,
                                              int ncol, u16* __restrict__ out, int idx) {
    int nt_cnt = ncol >> 4;
    int j    = idx & 7;
    int lane = (idx >> 3) & 63;
    int rest = idx >> 9;
    int nt   = rest % nt_cnt;
    int ks   = rest / nt_cnt;
    int col  = nt * 16 + (lane & 15);
    int k    = ks * 32 + ((lane >> 4) << 3) + j;
    float v = (k < 512) ? bases[(size_t)k * ncol + col] : root[(size_t)(k - 512) * ncol + col];
    out[idx] = f2b(v);
}

// ---------------- prep: Bsw repack + zero rowptr + zero scan state (all independent) ----------------
__global__ __launch_bounds__(256, 8) void prep_kernel(
    const float* __restrict__ Wp, const float* __restrict__ Wa,
    const float* __restrict__ bases0, const float* __restrict__ root0,
    const float* __restrict__ bases1, const float* __restrict__ root1,
    const float* __restrict__ bases2, const float* __restrict__ root2,
    u16* __restrict__ Bswp, u16* __restrict__ Bswa,
    u16* __restrict__ Bswc0, u16* __restrict__ Bswc1, u16* __restrict__ Bswc2,
    int* __restrict__ rowptr, u32* __restrict__ state) {
    int b = blockIdx.x, t = threadIdx.x;
    if (b < 1056) {
        if (b < 128)       bsw_proj_elem(Wp, Bswp, b * 256 + t);
        else if (b < 256)  bsw_proj_elem(Wa, Bswa, (b - 128) * 256 + t);
        else if (b < 576)  bsw_conv_elem(bases0, root0, HIDD, Bswc0, (b - 256) * 256 + t);
        else if (b < 896)  bsw_conv_elem(bases1, root1, HIDD, Bswc1, (b - 576) * 256 + t);
        else               bsw_conv_elem(bases2, root2, OUTD, Bswc2, (b - 896) * 256 + t);
    }
    int gtid  = b * 256 + t;
    int gsize = gridDim.x * 256;
    for (int i = gtid; i <= NSEG; i += gsize) rowptr[i] = 0;
    for (int i = gtid; i < NCHUNK; i += gsize) state[i] = 0;
}

// ---------------- hist (unchanged) ----------------
__global__ void hist_kernel(const int* __restrict__ ei, const int* __restrict__ et,
                            int* __restrict__ cnt) {
    int e = blockIdx.x * blockDim.x + threadIdx.x;
    if (e >= NEDGE) return;
    int dst = ei[NEDGE + e];
    int r   = et[e];
    atomicAdd(&cnt[dst * NREL + r], 1);
}

// ---------------- one-pass scan: replaces scan1+scan2+scan3 ----------------
// Block c: (A) local chunk scan; publish aggregate with bit31-ready release store.
// (B) aggregate-sum lookback: wave-parallel read of ALL predecessor aggregates
//     (no chaining, no arrival counter -> publishers never wait -> deadlock-free).
// (C) write rowptr (+prefix) and fill. Integer math -> bit-identical to 3-pass.
__global__ __launch_bounds__(256, 8) void scan_onepass(
    int* __restrict__ rowptr, int* __restrict__ fill, u32* __restrict__ state) {
    __shared__ int sh[256];
    int c = blockIdx.x, t = threadIdx.x;
    int base = c * 1024 + t * 4;
    int v[4];
#pragma unroll
    for (int i = 0; i < 4; i++) v[i] = (base + i <= NSEG) ? rowptr[base + i] : 0;
    int tot = v[0] + v[1] + v[2] + v[3];
    sh[t] = tot; __syncthreads();
    for (int off = 1; off < 256; off <<= 1) {
        int x = (t >= off) ? sh[t - off] : 0;
        __syncthreads();
        sh[t] += x;
        __syncthreads();
    }
    int excl = sh[t] - tot;
    if (t == 255)
        __hip_atomic_store(&state[c], (u32)sh[255] | RDY,
                           __ATOMIC_RELEASE, __HIP_MEMORY_SCOPE_AGENT);

    // lookback: prefix_c = sum of predecessor aggregates (each thread covers <=2)
    int part = 0;
    for (int i = t; i < c; i += 256) {
        u32 s; int spins = 0;
        for (;;) {
            s = __hip_atomic_load(&state[i], __ATOMIC_ACQUIRE, __HIP_MEMORY_SCOPE_AGENT);
            if (s & RDY) break;
            __builtin_amdgcn_s_sleep(2);
            if (++spins > (1 << 22)) break;      // safety escape -> wrong answer, not hang
        }
        part += (int)(s & 0x7fffffffu);
    }
    __syncthreads();                             // everyone done with sh from phase A
    sh[t] = part; __syncthreads();
    for (int off = 1; off < 256; off <<= 1) {
        int x = (t >= off) ? sh[t - off] : 0;
        __syncthreads();
        sh[t] += x;
        __syncthreads();
    }
    int prefix = sh[255];

    int run = excl + prefix;
#pragma unroll
    for (int i = 0; i < 4; i++) {
        int idx = base + i;
        if (idx <= NSEG) {
            rowptr[idx] = run;
            if (idx < NSEG) fill[idx] = run;
        }
        run += v[i];
    }
}

// ---------------- MFMA bf16 GEMM core (projections, unchanged) ----------------
template<int KMAIN, bool HASX, int NW, int MW, int NT, bool RELU, bool RES, bool AF32>
__device__ __forceinline__ void gemm_core(
    int blk, const void* __restrict__ Av, const u16* __restrict__ xq,
    const u16* __restrict__ Bsw, const float* __restrict__ bias, int M,
    float* __restrict__ out1, float* __restrict__ out2, u16* __restrict__ outb,
    const float* __restrict__ resid, int ldo) {
    constexpr int KSM = KMAIN / 32;
    constexpr int KST = KSM + (HASX ? 4 : 0);
    int tid  = threadIdx.x;
    int wave = tid >> 6, lane = tid & 63;
    int l15  = lane & 15, quad = lane >> 4;
    int rowbase = blk * (NW * MW * 16) + wave * (MW * 16);
    int rA[MW];
#pragma unroll
    for (int m = 0; m < MW; m++) {
        rA[m] = rowbase + m * 16 + l15;
        if (rA[m] > M - 1) rA[m] = M - 1;
    }
    const u16* bp = Bsw + lane * 8;
    f32x4 acc[MW][NT];
#pragma unroll
    for (int m = 0; m < MW; m++)
#pragma unroll
        for (int i = 0; i < NT; i++) acc[m][i] = (f32x4){0.f, 0.f, 0.f, 0.f};
#pragma unroll
    for (int ks = 0; ks < KST; ks++) {
        bf16x8 a[MW];
#pragma unroll
        for (int m = 0; m < MW; m++) {
            if (ks < KSM) {
                if (AF32) a[m] = cvt8((const float*)Av + (size_t)rA[m] * KMAIN + ks * 32 + quad * 8);
                else      a[m] = as_bf(*(const ushort8*)((const u16*)Av + (size_t)rA[m] * KMAIN + ks * 32 + quad * 8));
            } else {
                a[m] = as_bf(*(const ushort8*)(xq + (size_t)rA[m] * 128 + (ks - KSM) * 32 + quad * 8));
            }
        }
#pragma unroll
        for (int nt = 0; nt < NT; nt++) {
            bf16x8 b = as_bf(*(const ushort8*)(bp + ((size_t)(ks * NT + nt) << 9)));
#pragma unroll
            for (int m = 0; m < MW; m++)
                acc[m][nt] = __builtin_amdgcn_mfma_f32_16x16x32_bf16(a[m], b, acc[m][nt], 0, 0, 0);
        }
    }
#pragma unroll
    for (int m = 0; m < MW; m++) {
        int orow0 = rowbase + m * 16 + quad * 4;
#pragma unroll
        for (int r = 0; r < 4; r++) {
            int orow = orow0 + r;
            if (orow < M) {
#pragma unroll
                for (int nt = 0; nt < NT; nt++) {
                    int col = nt * 16 + l15;
                    float v = acc[m][nt][r] + bias[col];
                    if (RELU) v = v > 0.f ? v : 0.f;
                    if (RES)  v += resid[(size_t)orow * ldo + col];
                    size_t oi = (size_t)orow * ldo + col;
                    if (out1) out1[oi] = v;
                    if (out2) out2[oi] = v;
                    if (outb) outb[oi] = f2b(v);
                }
            }
        }
    }
}

// ---------------- scatter + projections fused (mutually independent work) ----------------
// blocks [0,391): paper proj | [391,782): author proj | [782,2048): scatter grid-stride
#define SPGRID 2048
__global__ __launch_bounds__(256, 2) void sp_kernel(
    const float* __restrict__ xp, const float* __restrict__ xa,
    const u16* __restrict__ Bswp, const u16* __restrict__ Bswa,
    const float* __restrict__ bp, const float* __restrict__ ba,
    float* __restrict__ lat0, float* __restrict__ lat1, u16* __restrict__ xbf0,
    const int* __restrict__ ei, const int* __restrict__ et,
    int* __restrict__ fill, int* __restrict__ epk) {
    int b = blockIdx.x;
    if (b < 782) {
        int y   = (b >= 391) ? 1 : 0;
        int blk = y ? b - 391 : b;
        const float* A    = y ? xa : xp;
        const u16*   B    = y ? Bswa : Bswp;
        const float* bias = y ? ba : bp;
        size_t off = (size_t)y * NPER * HIDD;
        gemm_core<256, false, 4, 1, 8, true, false, true>(
            blk, A, nullptr, B, bias, NPER, lat0 + off, lat1 + off, xbf0 + off, nullptr, HIDD);
    } else {
        int e0 = (b - 782) * 256 + threadIdx.x;
        const int estride = (SPGRID - 782) * 256;
        for (int e = e0; e < NEDGE; e += estride) {
            int src = ei[e];
            int dst = ei[NEDGE + e];
            int r   = et[e];
            int pos = atomicAdd(&fill[dst * NREL + r], 1);
            epk[pos] = src | (r << 16);
        }
    }
}

// ---------------- FUSED conv, 16-row M-tile (R4, proven) ----------------
template<int NT, bool RELU, bool RES>
__global__ __launch_bounds__(256, 8) void fused_conv16(
    const u16* __restrict__ xbf, const float* __restrict__ comp,
    const int* __restrict__ rowptr, const int* __restrict__ epk,
    const u16* __restrict__ Bsw, const float* __restrict__ bias,
    float* __restrict__ out1, u16* __restrict__ outb,
    const float* __restrict__ resid, int ldo) {
    __shared__ u16 As[16 * 512];           // 16 KB: 16 rows x 512 bf16 (4 bases x 128 ch)
    __shared__ float wtab[4][4][40];       // [wave][node][rel*4+b]; rel=8 slots are 0
    int tid  = threadIdx.x;
    int wv   = __builtin_amdgcn_readfirstlane(tid >> 6);
    int lane = tid & 63;
    int co   = lane * 2;
    float compv = (lane < 32) ? comp[lane] : 0.f;
    const int INV = 8 << 16;               // sentinel: src=0, rel=8 (zero weight)
    const u16* xco = xbf + co;

    int nbase = blockIdx.x * 16 + wv * 4;

    int p[4], e[4];
#pragma unroll
    for (int i = 0; i < 4; i++) {
        int rbase = (nbase + i) * NREL;
        if (lane < 36) {
            float w = 0.f;
            if (lane < 32) {
                int r   = lane >> 2;
                int c0  = rowptr[rbase + r], c1 = rowptr[rbase + r + 1];
                int cnt = c1 - c0;
                w = compv * ((cnt > 0) ? 1.f / (float)cnt : 0.f);
            }
            wtab[wv][i][lane] = w;
        }
        p[i] = __builtin_amdgcn_readfirstlane(rowptr[rbase]);
        e[i] = __builtin_amdgcn_readfirstlane(rowptr[rbase + 8]);
    }

#pragma unroll
    for (int i = 0; i < 4; i++) {
        int lr = wv * 4 + i;
        const char* wt = (const char*)&wtab[wv][i][0];
        f32x2 av[4];
#pragma unroll
        for (int b = 0; b < 4; b++) av[b] = (f32x2){0.f, 0.f};
        int k0[8]; u32 v0[8];
#pragma unroll
        for (int j = 0; j < 8; j++) k0[j] = (p[i] + j < e[i]) ? epk[p[i] + j] : INV;
#pragma unroll
        for (int j = 0; j < 8; j++) v0[j] = *(const u32*)(xco + ((size_t)(k0[j] & 0xffff) << 7));
        for (int pc = p[i]; pc < e[i]; pc += 8) {
            int pn = pc + 8;
            int k1[8]; u32 v1[8];
#pragma unroll
            for (int j = 0; j < 8; j++) k1[j] = (pn + j < e[i]) ? epk[pn + j] : INV;
#pragma unroll
            for (int j = 0; j < 8; j++) v1[j] = *(const u32*)(xco + ((size_t)(k1[j] & 0xffff) << 7));
#pragma unroll
            for (int j = 0; j < 8; j++) {
                f32x4 w = *(const f32x4*)(wt + (((u32)k0[j] >> 16) << 4));
                f32x2 x2; x2.x = blo(v0[j]); x2.y = bhi(v0[j]);
                av[0] += w[0] * x2;
                av[1] += w[1] * x2;
                av[2] += w[2] * x2;
                av[3] += w[3] * x2;
            }
#pragma unroll
            for (int j = 0; j < 8; j++) { k0[j] = k1[j]; v0[j] = v1[j]; }
        }
        u32 swz = (u32)(lr & 7) << 4;
        char* rowp = (char*)As + lr * 1024;
#pragma unroll
        for (int b = 0; b < 4; b++) {
            u32 pk = (u32)f2b(av[b].x) | ((u32)f2b(av[b].y) << 16);
            *(u32*)(rowp + (((u32)(b * 256 + lane * 4)) ^ swz)) = pk;
        }
    }
    __syncthreads();

    constexpr int NTW = NT / 4;
    int l15 = lane & 15, quad = lane >> 4;
    int rowbase = blockIdx.x * 16;
    int xrow = rowbase + l15;
    const u16*  bp   = Bsw + lane * 8;
    const char* arow = (const char*)As + l15 * 1024;
    u32 swz2 = (u32)(l15 & 7) << 4;
    f32x4 acc[NTW];
#pragma unroll
    for (int n = 0; n < NTW; n++) acc[n] = (f32x4){0.f, 0.f, 0.f, 0.f};
#pragma unroll
    for (int ks = 0; ks < 20; ks++) {
        bf16x8 a;
        if (ks < 16) a = *(const bf16x8*)(arow + (((u32)(ks * 64 + quad * 16)) ^ swz2));
        else         a = as_bf(*(const ushort8*)(xbf + (size_t)xrow * 128 + (ks - 16) * 32 + quad * 8));
#pragma unroll
        for (int n = 0; n < NTW; n++) {
            int nt = wv * NTW + n;
            bf16x8 b = as_bf(*(const ushort8*)(bp + ((size_t)(ks * NT + nt) << 9)));
            acc[n] = __builtin_amdgcn_mfma_f32_16x16x32_bf16(a, b, acc[n], 0, 0, 0);
        }
    }
    int orow0 = rowbase + quad * 4;
#pragma unroll
    for (int r = 0; r < 4; r++) {
        int orow = orow0 + r;
#pragma unroll
        for (int n = 0; n < NTW; n++) {
            int col = (wv * NTW + n) * 16 + l15;
            float v = acc[n][r] + bias[col];
            if (RELU) v = v > 0.f ? v : 0.f;
            if (RES)  v += resid[(size_t)orow * ldo + col];
            size_t oi = (size_t)orow * ldo + col;
            if (out1) out1[oi] = v;
            if (outb) outb[oi] = f2b(v);
        }
    }
}

extern "C" void kernel_launch(void* const* d_in, const int* in_sizes, int n_in,
                              void* d_out, int out_size, void* d_ws, size_t ws_size,
                              hipStream_t stream) {
    const float* x_paper  = (const float*)d_in[0];
    const float* x_author = (const float*)d_in[1];
    const float* W_paper  = (const float*)d_in[2];
    const float* b_paper  = (const float*)d_in[3];
    const float* W_author = (const float*)d_in[4];
    const float* b_author = (const float*)d_in[5];
    const float* bases0   = (const float*)d_in[6];
    const float* comp0    = (const float*)d_in[7];
    const float* root0    = (const float*)d_in[8];
    const float* bias0    = (const float*)d_in[9];
    const float* bases1   = (const float*)d_in[10];
    const float* comp1    = (const float*)d_in[11];
    const float* root1    = (const float*)d_in[12];
    const float* bias1    = (const float*)d_in[13];
    const float* bases2   = (const float*)d_in[14];
    const float* comp2    = (const float*)d_in[15];
    const float* root2    = (const float*)d_in[16];
    const float* bias2    = (const float*)d_in[17];
    const int* ei         = (const int*)d_in[18];
    const int* et         = (const int*)d_in[19];

    float* ob   = (float*)d_out;
    float* outF = ob;                         // [50000,64]
    float* lat0 = ob + 3200000;               // x0
    float* lat1 = ob + 9600000;               // x0 (copy)
    float* lat2 = ob + 16000000;              // x1

    char* w = (char*)d_ws;
    u16*   xbf0   = (u16*)(w + 51200000);     // 12,800,000
    u16*   xbf1   = (u16*)(w + 64000000);     // 12,800,000
    u16*   Bswc0  = (u16*)(w + 76800000);     // 163,840
    u16*   Bswc1  = (u16*)(w + 76963840);     // 163,840
    u16*   Bswc2  = (u16*)(w + 77127680);     // 81,920
    u16*   Bswp   = (u16*)(w + 77209600);     // 65,536
    u16*   Bswa   = (u16*)(w + 77275136);     // 65,536
    int*   rowptr = (int*)(w + 77340672);     // 400001*4 (pad to 1,600,064)
    int*   fill   = (int*)(w + 78940736);     // 1,600,000
    int*   epk    = (int*)(w + 80540736);     // 2,400,000
    u32*   state  = (u32*)(w + 82940736);     // 391*4 scan lookback state

    // ---- d1: Bsw repack + zero rowptr + zero scan state ----
    prep_kernel<<<2048, 256, 0, stream>>>(
        W_paper, W_author, bases0, root0, bases1, root1, bases2, root2,
        Bswp, Bswa, Bswc0, Bswc1, Bswc2, rowptr, state);

    // ---- d2: histogram over (dst, rel) ----
    hist_kernel<<<(NEDGE + 255) / 256, 256, 0, stream>>>(ei, et, rowptr);

    // ---- d3: one-pass exclusive scan (rowptr) + fill cursors ----
    scan_onepass<<<NCHUNK, 256, 0, stream>>>(rowptr, fill, state);

    // ---- d4: scatter + both projections (independent; fused) ----
    sp_kernel<<<SPGRID, 256, 0, stream>>>(
        x_paper, x_author, Bswp, Bswa, b_paper, b_author,
        lat0, lat1, xbf0, ei, et, fill, epk);

    // ---- d5-d7: RGCN convs ----
    int ngrid = NNODE / 16;                   // 3125 blocks, 16 nodes each
    fused_conv16<8, true, false><<<ngrid, 256, 0, stream>>>(
        xbf0, comp0, rowptr, epk, Bswc0, bias0, lat2, xbf1, nullptr, HIDD);
    fused_conv16<8, true, true><<<ngrid, 256, 0, stream>>>(
        xbf1, comp1, rowptr, epk, Bswc1, bias1, nullptr, xbf0, lat2, HIDD);
    fused_conv16<4, false, false><<<ngrid, 256, 0, stream>>>(
        xbf0, comp2, rowptr, epk, Bswc2, bias2, outF, nullptr, nullptr, OUTD);
}

// Round 8
// 390.678 us; speedup vs baseline: 8.3528x; 1.0205x over previous
//
#include <hip/hip_runtime.h>
#include <stdint.h>

#define NPER  25000
#define NNODE 50000
#define NEDGE 600000
#define NREL  8
#define NBASE 4
#define INDIM 256
#define HIDD  128
#define OUTD  64
#define NSEG  (NNODE * NREL)
#define NCHUNK ((NSEG + 1 + 1023) / 1024)   // 391 scan chunks
#define RDY   0x80000000u

typedef unsigned short u16;
typedef unsigned int   u32;
typedef __attribute__((ext_vector_type(8))) __bf16          bf16x8;
typedef __attribute__((ext_vector_type(8))) unsigned short  ushort8;
typedef __attribute__((ext_vector_type(4))) float           f32x4;
typedef __attribute__((ext_vector_type(2))) float           f32x2;

__device__ __forceinline__ u16 f2b(float f) {
    union { __bf16 h; u16 u; } v; v.h = (__bf16)f; return v.u;   // HW RNE cvt
}
__device__ __forceinline__ bf16x8 as_bf(ushort8 u) {
    union { ushort8 a; bf16x8 b; } v; v.a = u; return v.b;
}
__device__ __forceinline__ bf16x8 cvt8(const float* p) {
    f32x4 f0 = *(const f32x4*)p;
    f32x4 f1 = *(const f32x4*)(p + 4);
    ushort8 u;
#pragma unroll
    for (int i = 0; i < 4; i++) { u[i] = f2b(f0[i]); u[i + 4] = f2b(f1[i]); }
    return as_bf(u);
}
__device__ __forceinline__ float blo(u32 v) {
    union { u32 i; float f; } u; u.i = v << 16; return u.f;
}
__device__ __forceinline__ float bhi(u32 v) {
    union { u32 i; float f; } u; u.i = v & 0xffff0000u; return u.f;
}

// ---------------- Bsw repack element mappers (unchanged math) ----------------
__device__ __forceinline__ void bsw_proj_elem(const float* __restrict__ W, u16* __restrict__ out, int idx) {
    int j    = idx & 7;
    int lane = (idx >> 3) & 63;
    int rest = idx >> 9;
    int nt   = rest & 7;
    int ks   = rest >> 3;
    int col  = nt * 16 + (lane & 15);
    int k    = ks * 32 + ((lane >> 4) << 3) + j;
    out[idx] = f2b(W[(size_t)k * 128 + col]);
}
__device__ __forceinline__ void bsw_conv_elem(const float* __restrict__ bases, const float* __restrict__ root,
                                              int ncol, u16* __restrict__ out, int idx) {
    int nt_cnt = ncol >> 4;
    int j    = idx & 7;
    int lane = (idx >> 3) & 63;
    int rest = idx >> 9;
    int nt   = rest % nt_cnt;
    int ks   = rest / nt_cnt;
    int col  = nt * 16 + (lane & 15);
    int k    = ks * 32 + ((lane >> 4) << 3) + j;
    float v = (k < 512) ? bases[(size_t)k * ncol + col] : root[(size_t)(k - 512) * ncol + col];
    out[idx] = f2b(v);
}

// ---------------- prep: Bsw repack + zero rowptr + zero scan state (all independent) ----------------
__global__ __launch_bounds__(256, 8) void prep_kernel(
    const float* __restrict__ Wp, const float* __restrict__ Wa,
    const float* __restrict__ bases0, const float* __restrict__ root0,
    const float* __restrict__ bases1, const float* __restrict__ root1,
    const float* __restrict__ bases2, const float* __restrict__ root2,
    u16* __restrict__ Bswp, u16* __restrict__ Bswa,
    u16* __restrict__ Bswc0, u16* __restrict__ Bswc1, u16* __restrict__ Bswc2,
    int* __restrict__ rowptr, u32* __restrict__ state) {
    int b = blockIdx.x, t = threadIdx.x;
    if (b < 1056) {
        if (b < 128)       bsw_proj_elem(Wp, Bswp, b * 256 + t);
        else if (b < 256)  bsw_proj_elem(Wa, Bswa, (b - 128) * 256 + t);
        else if (b < 576)  bsw_conv_elem(bases0, root0, HIDD, Bswc0, (b - 256) * 256 + t);
        else if (b < 896)  bsw_conv_elem(bases1, root1, HIDD, Bswc1, (b - 576) * 256 + t);
        else               bsw_conv_elem(bases2, root2, OUTD, Bswc2, (b - 896) * 256 + t);
    }
    int gtid  = b * 256 + t;
    int gsize = gridDim.x * 256;
    for (int i = gtid; i <= NSEG; i += gsize) rowptr[i] = 0;
    for (int i = gtid; i < NCHUNK; i += gsize) state[i] = 0;
}

// ---------------- hist (unchanged) ----------------
__global__ void hist_kernel(const int* __restrict__ ei, const int* __restrict__ et,
                            int* __restrict__ cnt) {
    int e = blockIdx.x * blockDim.x + threadIdx.x;
    if (e >= NEDGE) return;
    int dst = ei[NEDGE + e];
    int r   = et[e];
    atomicAdd(&cnt[dst * NREL + r], 1);
}

// ---------------- one-pass scan: replaces scan1+scan2+scan3 ----------------
// Block c: (A) local chunk scan; publish aggregate with bit31-ready release store.
// (B) aggregate-sum lookback: wave-parallel read of ALL predecessor aggregates
//     (no chaining, no arrival counter -> publishers never wait -> deadlock-free).
// (C) write rowptr (+prefix) and fill. Integer math -> bit-identical to 3-pass.
__global__ __launch_bounds__(256, 8) void scan_onepass(
    int* __restrict__ rowptr, int* __restrict__ fill, u32* __restrict__ state) {
    __shared__ int sh[256];
    int c = blockIdx.x, t = threadIdx.x;
    int base = c * 1024 + t * 4;
    int v[4];
#pragma unroll
    for (int i = 0; i < 4; i++) v[i] = (base + i <= NSEG) ? rowptr[base + i] : 0;
    int tot = v[0] + v[1] + v[2] + v[3];
    sh[t] = tot; __syncthreads();
    for (int off = 1; off < 256; off <<= 1) {
        int x = (t >= off) ? sh[t - off] : 0;
        __syncthreads();
        sh[t] += x;
        __syncthreads();
    }
    int excl = sh[t] - tot;
    if (t == 255)
        __hip_atomic_store(&state[c], (u32)sh[255] | RDY,
                           __ATOMIC_RELEASE, __HIP_MEMORY_SCOPE_AGENT);

    // lookback: prefix_c = sum of predecessor aggregates (each thread covers <=2)
    int part = 0;
    for (int i = t; i < c; i += 256) {
        u32 s; int spins = 0;
        for (;;) {
            s = __hip_atomic_load(&state[i], __ATOMIC_ACQUIRE, __HIP_MEMORY_SCOPE_AGENT);
            if (s & RDY) break;
            __builtin_amdgcn_s_sleep(2);
            if (++spins > (1 << 22)) break;      // safety escape -> wrong answer, not hang
        }
        part += (int)(s & 0x7fffffffu);
    }
    __syncthreads();                             // everyone done with sh from phase A
    sh[t] = part; __syncthreads();
    for (int off = 1; off < 256; off <<= 1) {
        int x = (t >= off) ? sh[t - off] : 0;
        __syncthreads();
        sh[t] += x;
        __syncthreads();
    }
    int prefix = sh[255];

    int run = excl + prefix;
#pragma unroll
    for (int i = 0; i < 4; i++) {
        int idx = base + i;
        if (idx <= NSEG) {
            rowptr[idx] = run;
            if (idx < NSEG) fill[idx] = run;
        }
        run += v[i];
    }
}

// ---------------- scatter (standalone again: full occupancy, no launch-bound cap) ----------------
__global__ void scatter_kernel(const int* __restrict__ ei, const int* __restrict__ et,
                               int* __restrict__ fill, int* __restrict__ epk) {
    int e = blockIdx.x * blockDim.x + threadIdx.x;
    if (e >= NEDGE) return;
    int src = ei[e];
    int dst = ei[NEDGE + e];
    int r   = et[e];
    int pos = atomicAdd(&fill[dst * NREL + r], 1);
    epk[pos] = src | (r << 16);
}

// ---------------- MFMA bf16 GEMM core (projections, unchanged) ----------------
template<int KMAIN, bool HASX, int NW, int MW, int NT, bool RELU, bool RES, bool AF32>
__device__ __forceinline__ void gemm_core(
    int blk, const void* __restrict__ Av, const u16* __restrict__ xq,
    const u16* __restrict__ Bsw, const float* __restrict__ bias, int M,
    float* __restrict__ out1, float* __restrict__ out2, u16* __restrict__ outb,
    const float* __restrict__ resid, int ldo) {
    constexpr int KSM = KMAIN / 32;
    constexpr int KST = KSM + (HASX ? 4 : 0);
    int tid  = threadIdx.x;
    int wave = tid >> 6, lane = tid & 63;
    int l15  = lane & 15, quad = lane >> 4;
    int rowbase = blk * (NW * MW * 16) + wave * (MW * 16);
    int rA[MW];
#pragma unroll
    for (int m = 0; m < MW; m++) {
        rA[m] = rowbase + m * 16 + l15;
        if (rA[m] > M - 1) rA[m] = M - 1;
    }
    const u16* bp = Bsw + lane * 8;
    f32x4 acc[MW][NT];
#pragma unroll
    for (int m = 0; m < MW; m++)
#pragma unroll
        for (int i = 0; i < NT; i++) acc[m][i] = (f32x4){0.f, 0.f, 0.f, 0.f};
#pragma unroll
    for (int ks = 0; ks < KST; ks++) {
        bf16x8 a[MW];
#pragma unroll
        for (int m = 0; m < MW; m++) {
            if (ks < KSM) {
                if (AF32) a[m] = cvt8((const float*)Av + (size_t)rA[m] * KMAIN + ks * 32 + quad * 8);
                else      a[m] = as_bf(*(const ushort8*)((const u16*)Av + (size_t)rA[m] * KMAIN + ks * 32 + quad * 8));
            } else {
                a[m] = as_bf(*(const ushort8*)(xq + (size_t)rA[m] * 128 + (ks - KSM) * 32 + quad * 8));
            }
        }
#pragma unroll
        for (int nt = 0; nt < NT; nt++) {
            bf16x8 b = as_bf(*(const ushort8*)(bp + ((size_t)(ks * NT + nt) << 9)));
#pragma unroll
            for (int m = 0; m < MW; m++)
                acc[m][nt] = __builtin_amdgcn_mfma_f32_16x16x32_bf16(a[m], b, acc[m][nt], 0, 0, 0);
        }
    }
#pragma unroll
    for (int m = 0; m < MW; m++) {
        int orow0 = rowbase + m * 16 + quad * 4;
#pragma unroll
        for (int r = 0; r < 4; r++) {
            int orow = orow0 + r;
            if (orow < M) {
#pragma unroll
                for (int nt = 0; nt < NT; nt++) {
                    int col = nt * 16 + l15;
                    float v = acc[m][nt][r] + bias[col];
                    if (RELU) v = v > 0.f ? v : 0.f;
                    if (RES)  v += resid[(size_t)orow * ldo + col];
                    size_t oi = (size_t)orow * ldo + col;
                    if (out1) out1[oi] = v;
                    if (out2) out2[oi] = v;
                    if (outb) outb[oi] = f2b(v);
                }
            }
        }
    }
}

// both projections in one dispatch (gridDim.y = 2 selects paper/author)
__global__ __launch_bounds__(256, 2) void proj2_kernel(
    const float* __restrict__ xp, const float* __restrict__ xa,
    const u16* __restrict__ Bswp, const u16* __restrict__ Bswa,
    const float* __restrict__ bp, const float* __restrict__ ba,
    float* __restrict__ lat0, float* __restrict__ lat1, u16* __restrict__ xbf0) {
    int y = blockIdx.y;
    const float* A    = y ? xa : xp;
    const u16*   B    = y ? Bswa : Bswp;
    const float* bias = y ? ba : bp;
    size_t off = (size_t)y * NPER * HIDD;
    gemm_core<256, false, 4, 1, 8, true, false, true>(
        blockIdx.x, A, nullptr, B, bias, NPER, lat0 + off, lat1 + off, xbf0 + off, nullptr, HIDD);
}

// ---------------- FUSED conv, 16-row M-tile (R4, proven) ----------------
template<int NT, bool RELU, bool RES>
__global__ __launch_bounds__(256, 8) void fused_conv16(
    const u16* __restrict__ xbf, const float* __restrict__ comp,
    const int* __restrict__ rowptr, const int* __restrict__ epk,
    const u16* __restrict__ Bsw, const float* __restrict__ bias,
    float* __restrict__ out1, u16* __restrict__ outb,
    const float* __restrict__ resid, int ldo) {
    __shared__ u16 As[16 * 512];           // 16 KB: 16 rows x 512 bf16 (4 bases x 128 ch)
    __shared__ float wtab[4][4][40];       // [wave][node][rel*4+b]; rel=8 slots are 0
    int tid  = threadIdx.x;
    int wv   = __builtin_amdgcn_readfirstlane(tid >> 6);
    int lane = tid & 63;
    int co   = lane * 2;
    float compv = (lane < 32) ? comp[lane] : 0.f;
    const int INV = 8 << 16;               // sentinel: src=0, rel=8 (zero weight)
    const u16* xco = xbf + co;

    int nbase = blockIdx.x * 16 + wv * 4;

    int p[4], e[4];
#pragma unroll
    for (int i = 0; i < 4; i++) {
        int rbase = (nbase + i) * NREL;
        if (lane < 36) {
            float w = 0.f;
            if (lane < 32) {
                int r   = lane >> 2;
                int c0  = rowptr[rbase + r], c1 = rowptr[rbase + r + 1];
                int cnt = c1 - c0;
                w = compv * ((cnt > 0) ? 1.f / (float)cnt : 0.f);
            }
            wtab[wv][i][lane] = w;
        }
        p[i] = __builtin_amdgcn_readfirstlane(rowptr[rbase]);
        e[i] = __builtin_amdgcn_readfirstlane(rowptr[rbase + 8]);
    }

#pragma unroll
    for (int i = 0; i < 4; i++) {
        int lr = wv * 4 + i;
        const char* wt = (const char*)&wtab[wv][i][0];
        f32x2 av[4];
#pragma unroll
        for (int b = 0; b < 4; b++) av[b] = (f32x2){0.f, 0.f};
        int k0[8]; u32 v0[8];
#pragma unroll
        for (int j = 0; j < 8; j++) k0[j] = (p[i] + j < e[i]) ? epk[p[i] + j] : INV;
#pragma unroll
        for (int j = 0; j < 8; j++) v0[j] = *(const u32*)(xco + ((size_t)(k0[j] & 0xffff) << 7));
        for (int pc = p[i]; pc < e[i]; pc += 8) {
            int pn = pc + 8;
            int k1[8]; u32 v1[8];
#pragma unroll
            for (int j = 0; j < 8; j++) k1[j] = (pn + j < e[i]) ? epk[pn + j] : INV;
#pragma unroll
            for (int j = 0; j < 8; j++) v1[j] = *(const u32*)(xco + ((size_t)(k1[j] & 0xffff) << 7));
#pragma unroll
            for (int j = 0; j < 8; j++) {
                f32x4 w = *(const f32x4*)(wt + (((u32)k0[j] >> 16) << 4));
                f32x2 x2; x2.x = blo(v0[j]); x2.y = bhi(v0[j]);
                av[0] += w[0] * x2;
                av[1] += w[1] * x2;
                av[2] += w[2] * x2;
                av[3] += w[3] * x2;
            }
#pragma unroll
            for (int j = 0; j < 8; j++) { k0[j] = k1[j]; v0[j] = v1[j]; }
        }
        u32 swz = (u32)(lr & 7) << 4;
        char* rowp = (char*)As + lr * 1024;
#pragma unroll
        for (int b = 0; b < 4; b++) {
            u32 pk = (u32)f2b(av[b].x) | ((u32)f2b(av[b].y) << 16);
            *(u32*)(rowp + (((u32)(b * 256 + lane * 4)) ^ swz)) = pk;
        }
    }
    __syncthreads();

    constexpr int NTW = NT / 4;
    int l15 = lane & 15, quad = lane >> 4;
    int rowbase = blockIdx.x * 16;
    int xrow = rowbase + l15;
    const u16*  bp   = Bsw + lane * 8;
    const char* arow = (const char*)As + l15 * 1024;
    u32 swz2 = (u32)(l15 & 7) << 4;
    f32x4 acc[NTW];
#pragma unroll
    for (int n = 0; n < NTW; n++) acc[n] = (f32x4){0.f, 0.f, 0.f, 0.f};
#pragma unroll
    for (int ks = 0; ks < 20; ks++) {
        bf16x8 a;
        if (ks < 16) a = *(const bf16x8*)(arow + (((u32)(ks * 64 + quad * 16)) ^ swz2));
        else         a = as_bf(*(const ushort8*)(xbf + (size_t)xrow * 128 + (ks - 16) * 32 + quad * 8));
#pragma unroll
        for (int n = 0; n < NTW; n++) {
            int nt = wv * NTW + n;
            bf16x8 b = as_bf(*(const ushort8*)(bp + ((size_t)(ks * NT + nt) << 9)));
            acc[n] = __builtin_amdgcn_mfma_f32_16x16x32_bf16(a, b, acc[n], 0, 0, 0);
        }
    }
    int orow0 = rowbase + quad * 4;
#pragma unroll
    for (int r = 0; r < 4; r++) {
        int orow = orow0 + r;
#pragma unroll
        for (int n = 0; n < NTW; n++) {
            int col = (wv * NTW + n) * 16 + l15;
            float v = acc[n][r] + bias[col];
            if (RELU) v = v > 0.f ? v : 0.f;
            if (RES)  v += resid[(size_t)orow * ldo + col];
            size_t oi = (size_t)orow * ldo + col;
            if (out1) out1[oi] = v;
            if (outb) outb[oi] = f2b(v);
        }
    }
}

extern "C" void kernel_launch(void* const* d_in, const int* in_sizes, int n_in,
                              void* d_out, int out_size, void* d_ws, size_t ws_size,
                              hipStream_t stream) {
    const float* x_paper  = (const float*)d_in[0];
    const float* x_author = (const float*)d_in[1];
    const float* W_paper  = (const float*)d_in[2];
    const float* b_paper  = (const float*)d_in[3];
    const float* W_author = (const float*)d_in[4];
    const float* b_author = (const float*)d_in[5];
    const float* bases0   = (const float*)d_in[6];
    const float* comp0    = (const float*)d_in[7];
    const float* root0    = (const float*)d_in[8];
    const float* bias0    = (const float*)d_in[9];
    const float* bases1   = (const float*)d_in[10];
    const float* comp1    = (const float*)d_in[11];
    const float* root1    = (const float*)d_in[12];
    const float* bias1    = (const float*)d_in[13];
    const float* bases2   = (const float*)d_in[14];
    const float* comp2    = (const float*)d_in[15];
    const float* root2    = (const float*)d_in[16];
    const float* bias2    = (const float*)d_in[17];
    const int* ei         = (const int*)d_in[18];
    const int* et         = (const int*)d_in[19];

    float* ob   = (float*)d_out;
    float* outF = ob;                         // [50000,64]
    float* lat0 = ob + 3200000;               // x0
    float* lat1 = ob + 9600000;               // x0 (copy)
    float* lat2 = ob + 16000000;              // x1

    char* w = (char*)d_ws;
    u16*   xbf0   = (u16*)(w + 51200000);     // 12,800,000
    u16*   xbf1   = (u16*)(w + 64000000);     // 12,800,000
    u16*   Bswc0  = (u16*)(w + 76800000);     // 163,840
    u16*   Bswc1  = (u16*)(w + 76963840);     // 163,840
    u16*   Bswc2  = (u16*)(w + 77127680);     // 81,920
    u16*   Bswp   = (u16*)(w + 77209600);     // 65,536
    u16*   Bswa   = (u16*)(w + 77275136);     // 65,536
    int*   rowptr = (int*)(w + 77340672);     // 400001*4 (pad to 1,600,064)
    int*   fill   = (int*)(w + 78940736);     // 1,600,000
    int*   epk    = (int*)(w + 80540736);     // 2,400,000
    u32*   state  = (u32*)(w + 82940736);     // 391*4 scan lookback state

    // ---- d1: Bsw repack + zero rowptr + zero scan state ----
    prep_kernel<<<2048, 256, 0, stream>>>(
        W_paper, W_author, bases0, root0, bases1, root1, bases2, root2,
        Bswp, Bswa, Bswc0, Bswc1, Bswc2, rowptr, state);

    // ---- d2: histogram over (dst, rel) ----
    hist_kernel<<<(NEDGE + 255) / 256, 256, 0, stream>>>(ei, et, rowptr);

    // ---- d3: one-pass exclusive scan (rowptr) + fill cursors ----
    scan_onepass<<<NCHUNK, 256, 0, stream>>>(rowptr, fill, state);

    // ---- d4: scatter (full occupancy, standalone) ----
    scatter_kernel<<<(NEDGE + 255) / 256, 256, 0, stream>>>(ei, et, fill, epk);

    // ---- d5: projections x0 = relu(x @ W + b) ----
    proj2_kernel<<<dim3((NPER + 63) / 64, 2), 256, 0, stream>>>(
        x_paper, x_author, Bswp, Bswa, b_paper, b_author, lat0, lat1, xbf0);

    // ---- d6-d8: RGCN convs ----
    int ngrid = NNODE / 16;                   // 3125 blocks, 16 nodes each
    fused_conv16<8, true, false><<<ngrid, 256, 0, stream>>>(
        xbf0, comp0, rowptr, epk, Bswc0, bias0, lat2, xbf1, nullptr, HIDD);
    fused_conv16<8, true, true><<<ngrid, 256, 0, stream>>>(
        xbf1, comp1, rowptr, epk, Bswc1, bias1, nullptr, xbf0, lat2, HIDD);
    fused_conv16<4, false, false><<<ngrid, 256, 0, stream>>>(
        xbf0, comp2, rowptr, epk, Bswc2, bias2, outF, nullptr, nullptr, OUTD);
}

// Round 9
// 384.904 us; speedup vs baseline: 8.4782x; 1.0150x over previous
//
#include <hip/hip_runtime.h>
#include <stdint.h>

#define NPER  25000
#define NNODE 50000
#define NEDGE 600000
#define NREL  8
#define NBASE 4
#define INDIM 256
#define HIDD  128
#define OUTD  64
#define NSEG  (NNODE * NREL)

typedef unsigned short u16;
typedef unsigned int   u32;
typedef unsigned long long u64;
typedef __attribute__((ext_vector_type(8))) __bf16          bf16x8;
typedef __attribute__((ext_vector_type(8))) unsigned short  ushort8;
typedef __attribute__((ext_vector_type(4))) float           f32x4;
typedef __attribute__((ext_vector_type(2))) float           f32x2;

__device__ __forceinline__ u16 f2b(float f) {
    union { __bf16 h; u16 u; } v; v.h = (__bf16)f; return v.u;   // HW RNE cvt
}
__device__ __forceinline__ bf16x8 as_bf(ushort8 u) {
    union { ushort8 a; bf16x8 b; } v; v.a = u; return v.b;
}
__device__ __forceinline__ bf16x8 cvt8(const float* p) {
    f32x4 f0 = *(const f32x4*)p;
    f32x4 f1 = *(const f32x4*)(p + 4);
    ushort8 u;
#pragma unroll
    for (int i = 0; i < 4; i++) { u[i] = f2b(f0[i]); u[i + 4] = f2b(f1[i]); }
    return as_bf(u);
}
__device__ __forceinline__ float blo(u32 v) {
    union { u32 i; float f; } u; u.i = v << 16; return u.f;
}
__device__ __forceinline__ float bhi(u32 v) {
    union { u32 i; float f; } u; u.i = v & 0xffff0000u; return u.f;
}

// ---------------- fused weight repack: all 5 Bsw buffers in ONE kernel ----------------
__device__ __forceinline__ void bsw_proj_elem(const float* __restrict__ W, u16* __restrict__ out, int idx) {
    int j    = idx & 7;
    int lane = (idx >> 3) & 63;
    int rest = idx >> 9;
    int nt   = rest & 7;           // 128/16 = 8 col tiles
    int ks   = rest >> 3;
    int col  = nt * 16 + (lane & 15);
    int k    = ks * 32 + ((lane >> 4) << 3) + j;
    out[idx] = f2b(W[(size_t)k * 128 + col]);
}
__device__ __forceinline__ void bsw_conv_elem(const float* __restrict__ bases, const float* __restrict__ root,
                                              int ncol, u16* __restrict__ out, int idx) {
    int nt_cnt = ncol >> 4;
    int j    = idx & 7;
    int lane = (idx >> 3) & 63;
    int rest = idx >> 9;
    int nt   = rest % nt_cnt;
    int ks   = rest / nt_cnt;
    int col  = nt * 16 + (lane & 15);
    int k    = ks * 32 + ((lane >> 4) << 3) + j;
    float v = (k < 512) ? bases[(size_t)k * ncol + col] : root[(size_t)(k - 512) * ncol + col];
    out[idx] = f2b(v);
}
__global__ void build_bsw_all(const float* __restrict__ Wp, const float* __restrict__ Wa,
                              const float* __restrict__ bases0, const float* __restrict__ root0,
                              const float* __restrict__ bases1, const float* __restrict__ root1,
                              const float* __restrict__ bases2, const float* __restrict__ root2,
                              u16* __restrict__ Bswp, u16* __restrict__ Bswa,
                              u16* __restrict__ Bswc0, u16* __restrict__ Bswc1, u16* __restrict__ Bswc2) {
    int b = blockIdx.x, t = threadIdx.x;
    if (b < 128)       bsw_proj_elem(Wp, Bswp, b * 256 + t);
    else if (b < 256)  bsw_proj_elem(Wa, Bswa, (b - 128) * 256 + t);
    else if (b < 576)  bsw_conv_elem(bases0, root0, HIDD, Bswc0, (b - 256) * 256 + t);
    else if (b < 896)  bsw_conv_elem(bases1, root1, HIDD, Bswc1, (b - 576) * 256 + t);
    else               bsw_conv_elem(bases2, root2, OUTD, Bswc2, (b - 896) * 256 + t);
}

// ---------------- CSR build over seg = dst*8 + etype (R4's proven 3-pass) ----------------
__global__ void hist_kernel(const int* __restrict__ ei, const int* __restrict__ et,
                            int* __restrict__ cnt) {
    int e = blockIdx.x * blockDim.x + threadIdx.x;
    if (e >= NEDGE) return;
    int dst = ei[NEDGE + e];
    int r   = et[e];
    atomicAdd(&cnt[dst * NREL + r], 1);
}

#define SCAN_CHUNK 1024
__global__ void scan1_kernel(int* __restrict__ data, int n, int* __restrict__ bsum) {
    __shared__ int sh[256];
    int t = threadIdx.x;
    int base = blockIdx.x * SCAN_CHUNK + t * 4;
    int v[4];
#pragma unroll
    for (int i = 0; i < 4; i++) v[i] = (base + i < n) ? data[base + i] : 0;
    int tot = v[0] + v[1] + v[2] + v[3];
    sh[t] = tot; __syncthreads();
    for (int off = 1; off < 256; off <<= 1) {
        int x = (t >= off) ? sh[t - off] : 0;
        __syncthreads();
        sh[t] += x;
        __syncthreads();
    }
    int excl = sh[t] - tot;
    if (t == 255) bsum[blockIdx.x] = sh[255];
    int run = excl;
#pragma unroll
    for (int i = 0; i < 4; i++) {
        if (base + i < n) data[base + i] = run;
        run += v[i];
    }
}

__global__ void scan2_kernel(int* __restrict__ bsum, int nb) {
    __shared__ int sh[512];
    int t = threadIdx.x;
    int v = (t < nb) ? bsum[t] : 0;
    sh[t] = v; __syncthreads();
    for (int off = 1; off < 512; off <<= 1) {
        int x = (t >= off) ? sh[t - off] : 0;
        __syncthreads();
        sh[t] += x;
        __syncthreads();
    }
    if (t < nb) bsum[t] = sh[t] - v;
}

__global__ void scan3_kernel(int* __restrict__ data, int n, const int* __restrict__ bsum,
                             int* __restrict__ fill) {
    int add = bsum[blockIdx.x];
    int base = blockIdx.x * SCAN_CHUNK + threadIdx.x * 4;
#pragma unroll
    for (int i = 0; i < 4; i++) {
        int idx = base + i;
        if (idx < n) {
            int v = data[idx] + add;
            data[idx] = v;
            if (idx < NSEG) fill[idx] = v;
        }
    }
}

__global__ void scatter_kernel(const int* __restrict__ ei, const int* __restrict__ et,
                               int* __restrict__ fill, int* __restrict__ epk) {
    int e = blockIdx.x * blockDim.x + threadIdx.x;
    if (e >= NEDGE) return;
    int src = ei[e];
    int dst = ei[NEDGE + e];
    int r   = et[e];
    int pos = atomicAdd(&fill[dst * NREL + r], 1);
    epk[pos] = src | (r << 16);
}

// ---------------- FUSED conv, 16-row M-tile, PAIRED half-wave gather ----------------
// R9 change vs R4: phase-1 walk restructured. Lanes 0-31 walk node 2s, lanes
// 32-63 walk node 2s+1 CONCURRENTLY (s = 0,1): serial node depth per wave 4 -> 2,
// each lane covers 4 channels (u64 x-loads, 8 B/lane), pipeline depth 4 x 2
// halves = 8 edges in flight (same MLP as R4, ~56 VGPR, still 8 blocks/CU).
// Per-channel FMA order unchanged (ascending epk) -> bit-identical output.
template<int NT, bool RELU, bool RES>
__global__ __launch_bounds__(256, 8) void fused_conv16(
    const u16* __restrict__ xbf, const float* __restrict__ comp,
    const int* __restrict__ rowptr, const int* __restrict__ epk,
    const u16* __restrict__ Bsw, const float* __restrict__ bias,
    float* __restrict__ out1, u16* __restrict__ outb,
    const float* __restrict__ resid, int ldo) {
    __shared__ u16 As[16 * 512];           // 16 KB: 16 rows x 512 bf16 (4 bases x 128 ch)
    __shared__ float wtab[4][4][40];       // [wave][node][rel*4+b]; rel=8 slots are 0
    int tid  = threadIdx.x;
    int wv   = __builtin_amdgcn_readfirstlane(tid >> 6);
    int lane = tid & 63;
    int half = lane >> 5;                  // 0: walks node 2s, 1: walks node 2s+1
    int hl   = lane & 31;                  // lane-in-half; owns channels 4*hl..4*hl+3
    float compv = (lane < 32) ? comp[lane] : 0.f;
    const int INV = 8 << 16;               // sentinel: src=0, rel=8 (zero weight)
    const u16* xq4 = xbf + hl * 4;         // per-lane channel base (u64 = 4 ch)

    int nbase = blockIdx.x * 16 + wv * 4;  // grid*16 == NNODE exactly; no bounds checks

    // ---- hoisted per-node state ----
    int p[4], e[4];
#pragma unroll
    for (int i = 0; i < 4; i++) {
        int rbase = (nbase + i) * NREL;
        if (lane < 36) {
            float w = 0.f;
            if (lane < 32) {
                int r   = lane >> 2;
                int c0  = rowptr[rbase + r], c1 = rowptr[rbase + r + 1];
                int cnt = c1 - c0;
                w = compv * ((cnt > 0) ? 1.f / (float)cnt : 0.f);
            }
            wtab[wv][i][lane] = w;
        }
        p[i] = __builtin_amdgcn_readfirstlane(rowptr[rbase]);
        e[i] = __builtin_amdgcn_readfirstlane(rowptr[rbase + 8]);
    }

    // ---- phase 1: two nodes per wave in parallel (one per half-wave), s = pair idx ----
#pragma unroll
    for (int s = 0; s < 2; s++) {
        int pm  = half ? p[2 * s + 1] : p[2 * s];
        int em  = half ? e[2 * s + 1] : e[2 * s];
        int len = em - pm;
        int lenA = __builtin_amdgcn_readlane(len, 0);
        int lenB = __builtin_amdgcn_readlane(len, 32);
        int mlen = lenA > lenB ? lenA : lenB;      // wave-uniform loop bound
        const char* wt = (const char*)&wtab[wv][2 * s][0] + half * 160;  // 40 floats/node
        f32x2 av0[4], av1[4];                      // ch{4hl,4hl+1} / ch{4hl+2,4hl+3} x 4 bases
#pragma unroll
        for (int b = 0; b < 4; b++) { av0[b] = (f32x2){0.f, 0.f}; av1[b] = (f32x2){0.f, 0.f}; }
        int k0[4]; u64 v0[4];
#pragma unroll
        for (int j = 0; j < 4; j++) k0[j] = (j < len) ? epk[pm + j] : INV;
#pragma unroll
        for (int j = 0; j < 4; j++) v0[j] = *(const u64*)(xq4 + ((size_t)(k0[j] & 0xffff) << 7));
        for (int jc = 0; jc < mlen; jc += 4) {
            int jn = jc + 4;
            int k1[4]; u64 v1[4];
#pragma unroll
            for (int j = 0; j < 4; j++) k1[j] = (jn + j < len) ? epk[pm + jn + j] : INV;
#pragma unroll
            for (int j = 0; j < 4; j++) v1[j] = *(const u64*)(xq4 + ((size_t)(k1[j] & 0xffff) << 7));
#pragma unroll
            for (int j = 0; j < 4; j++) {
                // one 16 B LDS broadcast per half (2 addrs/wave, <=2-way: free)
                f32x4 w = *(const f32x4*)(wt + (((u32)k0[j] >> 16) << 4));
                u32 lo = (u32)v0[j], hi = (u32)(v0[j] >> 32);
                f32x2 xa; xa.x = blo(lo); xa.y = bhi(lo);
                f32x2 xb; xb.x = blo(hi); xb.y = bhi(hi);
                av0[0] += w[0] * xa; av1[0] += w[0] * xb;
                av0[1] += w[1] * xa; av1[1] += w[1] * xb;
                av0[2] += w[2] * xa; av1[2] += w[2] * xb;
                av0[3] += w[3] * xa; av1[3] += w[3] * xb;
            }
#pragma unroll
            for (int j = 0; j < 4; j++) { k0[j] = k1[j]; v0[j] = v1[j]; }
        }
        // write row: ch = 4*hl.. as u64 at byte (b*256 + hl*8) ^ swz -> identical
        // final LDS content to R4 (ch*2 byte mapping, XOR bit4 swizzle preserved)
        int lr = wv * 4 + 2 * s + half;
        u32 swz = (u32)(lr & 7) << 4;
        char* rowp = (char*)As + lr * 1024;
#pragma unroll
        for (int b = 0; b < 4; b++) {
            u32 pklo = (u32)f2b(av0[b].x) | ((u32)f2b(av0[b].y) << 16);
            u32 pkhi = (u32)f2b(av1[b].x) | ((u32)f2b(av1[b].y) << 16);
            u64 pk = (u64)pklo | ((u64)pkhi << 32);
            *(u64*)(rowp + (((u32)(b * 256 + hl * 8)) ^ swz)) = pk;
        }
    }
    __syncthreads();

    // ---- phase 2: [16 x 640] @ [640 x NT*16] MFMA; wave handles NT/4 col tiles ----
    constexpr int NTW = NT / 4;
    int l15 = lane & 15, quad = lane >> 4;
    int rowbase = blockIdx.x * 16;
    int xrow = rowbase + l15;              // always < NNODE
    const u16*  bp   = Bsw + lane * 8;
    const char* arow = (const char*)As + l15 * 1024;
    u32 swz2 = (u32)(l15 & 7) << 4;
    f32x4 acc[NTW];
#pragma unroll
    for (int n = 0; n < NTW; n++) acc[n] = (f32x4){0.f, 0.f, 0.f, 0.f};
#pragma unroll
    for (int ks = 0; ks < 20; ks++) {
        bf16x8 a;
        if (ks < 16) a = *(const bf16x8*)(arow + (((u32)(ks * 64 + quad * 16)) ^ swz2));
        else         a = as_bf(*(const ushort8*)(xbf + (size_t)xrow * 128 + (ks - 16) * 32 + quad * 8));
#pragma unroll
        for (int n = 0; n < NTW; n++) {
            int nt = wv * NTW + n;
            bf16x8 b = as_bf(*(const ushort8*)(bp + ((size_t)(ks * NT + nt) << 9)));
            acc[n] = __builtin_amdgcn_mfma_f32_16x16x32_bf16(a, b, acc[n], 0, 0, 0);
        }
    }
    int orow0 = rowbase + quad * 4;
#pragma unroll
    for (int r = 0; r < 4; r++) {
        int orow = orow0 + r;
#pragma unroll
        for (int n = 0; n < NTW; n++) {
            int col = (wv * NTW + n) * 16 + l15;
            float v = acc[n][r] + bias[col];
            if (RELU) v = v > 0.f ? v : 0.f;
            if (RES)  v += resid[(size_t)orow * ldo + col];
            size_t oi = (size_t)orow * ldo + col;
            if (out1) out1[oi] = v;
            if (outb) outb[oi] = f2b(v);
        }
    }
}

// ---------------- MFMA bf16 GEMM core (projections) ----------------
template<int KMAIN, bool HASX, int NW, int MW, int NT, bool RELU, bool RES, bool AF32>
__device__ __forceinline__ void gemm_core(
    int blk, const void* __restrict__ Av, const u16* __restrict__ xq,
    const u16* __restrict__ Bsw, const float* __restrict__ bias, int M,
    float* __restrict__ out1, float* __restrict__ out2, u16* __restrict__ outb,
    const float* __restrict__ resid, int ldo) {
    constexpr int KSM = KMAIN / 32;
    constexpr int KST = KSM + (HASX ? 4 : 0);
    int tid  = threadIdx.x;
    int wave = tid >> 6, lane = tid & 63;
    int l15  = lane & 15, quad = lane >> 4;
    int rowbase = blk * (NW * MW * 16) + wave * (MW * 16);
    int rA[MW];
#pragma unroll
    for (int m = 0; m < MW; m++) {
        rA[m] = rowbase + m * 16 + l15;
        if (rA[m] > M - 1) rA[m] = M - 1;
    }
    const u16* bp = Bsw + lane * 8;
    f32x4 acc[MW][NT];
#pragma unroll
    for (int m = 0; m < MW; m++)
#pragma unroll
        for (int i = 0; i < NT; i++) acc[m][i] = (f32x4){0.f, 0.f, 0.f, 0.f};
#pragma unroll
    for (int ks = 0; ks < KST; ks++) {
        bf16x8 a[MW];
#pragma unroll
        for (int m = 0; m < MW; m++) {
            if (ks < KSM) {
                if (AF32) a[m] = cvt8((const float*)Av + (size_t)rA[m] * KMAIN + ks * 32 + quad * 8);
                else      a[m] = as_bf(*(const ushort8*)((const u16*)Av + (size_t)rA[m] * KMAIN + ks * 32 + quad * 8));
            } else {
                a[m] = as_bf(*(const ushort8*)(xq + (size_t)rA[m] * 128 + (ks - KSM) * 32 + quad * 8));
            }
        }
#pragma unroll
        for (int nt = 0; nt < NT; nt++) {
            bf16x8 b = as_bf(*(const ushort8*)(bp + ((size_t)(ks * NT + nt) << 9)));
#pragma unroll
            for (int m = 0; m < MW; m++)
                acc[m][nt] = __builtin_amdgcn_mfma_f32_16x16x32_bf16(a[m], b, acc[m][nt], 0, 0, 0);
        }
    }
#pragma unroll
    for (int m = 0; m < MW; m++) {
        int orow0 = rowbase + m * 16 + quad * 4;
#pragma unroll
        for (int r = 0; r < 4; r++) {
            int orow = orow0 + r;
            if (orow < M) {
#pragma unroll
                for (int nt = 0; nt < NT; nt++) {
                    int col = nt * 16 + l15;
                    float v = acc[m][nt][r] + bias[col];
                    if (RELU) v = v > 0.f ? v : 0.f;
                    if (RES)  v += resid[(size_t)orow * ldo + col];
                    size_t oi = (size_t)orow * ldo + col;
                    if (out1) out1[oi] = v;
                    if (out2) out2[oi] = v;
                    if (outb) outb[oi] = f2b(v);
                }
            }
        }
    }
}

// both projections in one dispatch (gridDim.y = 2 selects paper/author)
__global__ __launch_bounds__(256, 2) void proj2_kernel(
    const float* __restrict__ xp, const float* __restrict__ xa,
    const u16* __restrict__ Bswp, const u16* __restrict__ Bswa,
    const float* __restrict__ bp, const float* __restrict__ ba,
    float* __restrict__ lat0, float* __restrict__ lat1, u16* __restrict__ xbf0) {
    int y = blockIdx.y;
    const float* A    = y ? xa : xp;
    const u16*   B    = y ? Bswa : Bswp;
    const float* bias = y ? ba : bp;
    size_t off = (size_t)y * NPER * HIDD;
    gemm_core<256, false, 4, 1, 8, true, false, true>(
        blockIdx.x, A, nullptr, B, bias, NPER, lat0 + off, lat1 + off, xbf0 + off, nullptr, HIDD);
}

extern "C" void kernel_launch(void* const* d_in, const int* in_sizes, int n_in,
                              void* d_out, int out_size, void* d_ws, size_t ws_size,
                              hipStream_t stream) {
    const float* x_paper  = (const float*)d_in[0];
    const float* x_author = (const float*)d_in[1];
    const float* W_paper  = (const float*)d_in[2];
    const float* b_paper  = (const float*)d_in[3];
    const float* W_author = (const float*)d_in[4];
    const float* b_author = (const float*)d_in[5];
    const float* bases0   = (const float*)d_in[6];
    const float* comp0    = (const float*)d_in[7];
    const float* root0    = (const float*)d_in[8];
    const float* bias0    = (const float*)d_in[9];
    const float* bases1   = (const float*)d_in[10];
    const float* comp1    = (const float*)d_in[11];
    const float* root1    = (const float*)d_in[12];
    const float* bias1    = (const float*)d_in[13];
    const float* bases2   = (const float*)d_in[14];
    const float* comp2    = (const float*)d_in[15];
    const float* root2    = (const float*)d_in[16];
    const float* bias2    = (const float*)d_in[17];
    const int* ei         = (const int*)d_in[18];
    const int* et         = (const int*)d_in[19];

    float* ob   = (float*)d_out;
    float* outF = ob;                         // [50000,64]
    float* lat0 = ob + 3200000;               // x0
    float* lat1 = ob + 9600000;               // x0 (copy)
    float* lat2 = ob + 16000000;              // x1

    char* w = (char*)d_ws;
    u16*   xbf0   = (u16*)(w + 51200000);     // 12,800,000
    u16*   xbf1   = (u16*)(w + 64000000);     // 12,800,000
    u16*   Bswc0  = (u16*)(w + 76800000);     // 163,840
    u16*   Bswc1  = (u16*)(w + 76963840);     // 163,840
    u16*   Bswc2  = (u16*)(w + 77127680);     // 81,920
    u16*   Bswp   = (u16*)(w + 77209600);     // 65,536
    u16*   Bswa   = (u16*)(w + 77275136);     // 65,536
    int*   rowptr = (int*)(w + 77340672);     // 400001*4 (pad to 1,600,064)
    int*   fill   = (int*)(w + 78940736);     // 1,600,000
    int*   epk    = (int*)(w + 80540736);     // 2,400,000
    int*   bsum   = (int*)(w + 82940736);     // 2,048

    // ---- all weight repacks, one dispatch ----
    build_bsw_all<<<1056, 256, 0, stream>>>(W_paper, W_author, bases0, root0,
                                            bases1, root1, bases2, root2,
                                            Bswp, Bswa, Bswc0, Bswc1, Bswc2);

    // ---- projections: x0 = relu(x @ W + b) -> lat0, lat1 (fp32) + xbf0 (bf16) ----
    proj2_kernel<<<dim3((NPER + 63) / 64, 2), 256, 0, stream>>>(
        x_paper, x_author, Bswp, Bswa, b_paper, b_author, lat0, lat1, xbf0);

    // ---- CSR over (dst, rel) segments (shared by all 3 convs) ----
    hipMemsetAsync(rowptr, 0, (NSEG + 1) * sizeof(int), stream);
    hist_kernel<<<(NEDGE + 255) / 256, 256, 0, stream>>>(ei, et, rowptr);
    int nchunk = (NSEG + 1 + SCAN_CHUNK - 1) / SCAN_CHUNK;   // 391
    scan1_kernel<<<nchunk, 256, 0, stream>>>(rowptr, NSEG + 1, bsum);
    scan2_kernel<<<1, 512, 0, stream>>>(bsum, nchunk);
    scan3_kernel<<<nchunk, 256, 0, stream>>>(rowptr, NSEG + 1, bsum, fill);
    scatter_kernel<<<(NEDGE + 255) / 256, 256, 0, stream>>>(ei, et, fill, epk);

    int ngrid = NNODE / 16;                   // 3125 blocks, 16 nodes each

    // ---- conv0: x1 = relu(rgcn(x0)) -> lat2 (fp32) + xbf1 (bf16) ----
    fused_conv16<8, true, false><<<ngrid, 256, 0, stream>>>(
        xbf0, comp0, rowptr, epk, Bswc0, bias0, lat2, xbf1, nullptr, HIDD);

    // ---- conv1: x2 = x1 + relu(rgcn(x1)) -> xbf0 (bf16 only; x2 not an output) ----
    fused_conv16<8, true, true><<<ngrid, 256, 0, stream>>>(
        xbf1, comp1, rowptr, epk, Bswc1, bias1, nullptr, xbf0, lat2, HIDD);

    // ---- conv2: out = rgcn(x2) (no relu) -> outF fp32 ----
    fused_conv16<4, false, false><<<ngrid, 256, 0, stream>>>(
        xbf0, comp2, rowptr, epk, Bswc2, bias2, outF, nullptr, nullptr, OUTD);
}